// Round 4
// baseline (435.204 us; speedup 1.0000x reference)
//
#include <hip/hip_runtime.h>
#include <math.h>

#define B_   8
#define C_   256
#define N_   4096
#define CQK_ 64
#define JS_  8
#define NSPLIT 2
#define NRANGE (N_ / NSPLIT)   // 2048

typedef __attribute__((ext_vector_type(8))) short short8v;   // 8 x bf16 (4 VGPRs)
typedef __attribute__((ext_vector_type(4))) short short4v;   // 4 x bf16 (8B)
typedef __attribute__((ext_vector_type(4))) float f32x4;

__device__ __forceinline__ unsigned short f2bf(float f) {
    unsigned u = __float_as_uint(f);
    u += 0x7fffu + ((u >> 16) & 1u);
    return (unsigned short)(u >> 16);
}
__device__ __forceinline__ float bf2f(unsigned short h) {
    return __uint_as_float((unsigned)h << 16);
}

// ------------------------------------------------ weights fp32 -> bf16 (row-major, packed)
__global__ __launch_bounds__(256) void wcvt_kernel(const float* __restrict__ wqk,
                                                   const float* __restrict__ wv,
                                                   const float* __restrict__ wt,
                                                   unsigned short* __restrict__ wh) {
    int i = (blockIdx.x * 256 + threadIdx.x) * 4;   // 144*256*4 = 147456 total
    const float* src; int off;
    if (i < 16384)      { src = wqk; off = i; }
    else if (i < 81920) { src = wv;  off = i - 16384; }
    else                { src = wt;  off = i - 81920; }
    float4 v = *(const float4*)(src + off);
    short4v o;
    o[0] = (short)f2bf(v.x); o[1] = (short)f2bf(v.y);
    o[2] = (short)f2bf(v.z); o[3] = (short)f2bf(v.w);
    *(short4v*)(wh + i) = o;
}

// --------------------------- xs = x + xyz (fp32 [b][c][n]) AND xst bf16 transposed [b][n][c]
__global__ __launch_bounds__(256) void addt_kernel(const float* __restrict__ x,
                                                   const float* __restrict__ xyz,
                                                   float* __restrict__ xs,
                                                   unsigned short* __restrict__ xst) {
    __shared__ float st[64][65];
    const int tid = threadIdx.x;
    const int n0 = blockIdx.x * 64, c0 = blockIdx.y * 64, b = blockIdx.z;
    const size_t base = ((size_t)b * C_ + c0) * N_ + n0;
#pragma unroll
    for (int r = 0; r < 4; ++r) {
        int c = r * 16 + (tid >> 4);
        int nc = (tid & 15) * 4;
        size_t off = base + (size_t)c * N_ + nc;
        float4 xv = *(const float4*)(x + off);
        float4 yv = *(const float4*)(xyz + off);
        float4 s = make_float4(xv.x + yv.x, xv.y + yv.y, xv.z + yv.z, xv.w + yv.w);
        *(float4*)(xs + off) = s;
        st[c][nc] = s.x; st[c][nc + 1] = s.y; st[c][nc + 2] = s.z; st[c][nc + 3] = s.w;
    }
    __syncthreads();
    int n = tid >> 2, cc = (tid & 3) * 16;
    short8v p0, p1;
#pragma unroll
    for (int j = 0; j < 8; ++j) {
        p0[j] = (short)f2bf(st[cc + j][n]);
        p1[j] = (short)f2bf(st[cc + 8 + j][n]);
    }
    size_t ob = ((size_t)b * N_ + n0 + n) * 256 + c0 + cc;
    *(short8v*)(xst + ob) = p0;
    *(short8v*)(xst + ob + 8) = p1;
}

// --------------------- Q-conv (MFMA): out Qt[b][n][64] bf16
__global__ __launch_bounds__(256, 4) void convq_kernel(const unsigned short* __restrict__ xst,
                                                       const unsigned short* __restrict__ wh,
                                                       const float* __restrict__ bias,
                                                       unsigned short* __restrict__ Qt) {
    const int tid = threadIdx.x, wave = tid >> 6, lane = tid & 63, q = lane & 15, g = lane >> 4;
    const int n0 = blockIdx.x * 64, b = blockIdx.y;
    const unsigned short* xb = xst + (size_t)b * N_ * 256;
    f32x4 acc[4];
#pragma unroll
    for (int j = 0; j < 4; ++j) acc[j] = (f32x4){0.f, 0.f, 0.f, 0.f};
    for (int ks = 0; ks < 8; ++ks) {
        short8v aw = *(const short8v*)(wh + (size_t)(wave * 16 + q) * 256 + ks * 32 + 8 * g);
#pragma unroll
        for (int j = 0; j < 4; ++j) {
            short8v bx = *(const short8v*)(xb + (size_t)(n0 + j * 16 + q) * 256 + ks * 32 + 8 * g);
            acc[j] = __builtin_amdgcn_mfma_f32_16x16x32_bf16(aw, bx, acc[j], 0, 0, 0);
        }
    }
#pragma unroll
    for (int j = 0; j < 4; ++j) {
        short4v pk;
#pragma unroll
        for (int r = 0; r < 4; ++r)
            pk[r] = (short)f2bf(acc[j][r] + bias[wave * 16 + 4 * g + r]);
        *(short4v*)(Qt + ((size_t)b * N_ + n0 + j * 16 + q) * 64 + wave * 16 + 4 * g) = pk;
    }
}

// --------------------- V-conv (MFMA): out Vh[b][c][n] bf16
__global__ __launch_bounds__(256, 4) void convv_kernel(const unsigned short* __restrict__ xst,
                                                       const unsigned short* __restrict__ wh,
                                                       const float* __restrict__ bias,
                                                       unsigned short* __restrict__ Vh) {
    const int tid = threadIdx.x, wave = tid >> 6, lane = tid & 63, q = lane & 15, g = lane >> 4;
    const int n0 = blockIdx.x * 64, o0 = blockIdx.y * 64, b = blockIdx.z;
    const unsigned short* xb = xst + (size_t)b * N_ * 256;
    f32x4 acc[4];
#pragma unroll
    for (int j = 0; j < 4; ++j) acc[j] = (f32x4){0.f, 0.f, 0.f, 0.f};
    for (int ks = 0; ks < 8; ++ks) {
        short8v bw = *(const short8v*)(wh + (size_t)(o0 + wave * 16 + q) * 256 + ks * 32 + 8 * g);
#pragma unroll
        for (int j = 0; j < 4; ++j) {
            short8v ax = *(const short8v*)(xb + (size_t)(n0 + j * 16 + q) * 256 + ks * 32 + 8 * g);
            acc[j] = __builtin_amdgcn_mfma_f32_16x16x32_bf16(ax, bw, acc[j], 0, 0, 0);
        }
    }
    float bo = bias[o0 + wave * 16 + q];
#pragma unroll
    for (int j = 0; j < 4; ++j) {
        short4v pk;
#pragma unroll
        for (int r = 0; r < 4; ++r) pk[r] = (short)f2bf(acc[j][r] + bo);
        *(short4v*)(Vh + ((size_t)b * C_ + o0 + wave * 16 + q) * N_ + n0 + j * 16 + 4 * g) = pk;
    }
}

// ------------------------------------------- pass A: per-row online softmax stats via MFMA
__global__ __launch_bounds__(256) void rowstats_mfma(const unsigned short* __restrict__ Qt,
                                                     float* __restrict__ pmax,
                                                     float* __restrict__ psum) {
    const int tid = threadIdx.x;
    const int wave = tid >> 6, lane = tid & 63, q = lane & 15, g = lane >> 4;
    const int bid = blockIdx.x;
    const int b  = bid & 7;
    const int it = (bid >> 3) & 63;
    const int js = bid >> 9;
    const int i0 = it * 64 + wave * 16;
    const unsigned short* Qb = Qt + (size_t)b * N_ * CQK_;

    const unsigned short* bp = Qb + (size_t)(i0 + q) * CQK_ + 8 * g;
    short8v bq0 = *(const short8v*)bp;
    short8v bq1 = *(const short8v*)(bp + 32);

    float m = -1e30f, s = 0.f;
    const int jbeg = js * (N_ / JS_);
    for (int j0 = jbeg; j0 < jbeg + N_ / JS_; j0 += 16) {
        const unsigned short* ap = Qb + (size_t)(j0 + q) * CQK_ + 8 * g;
        short8v a0 = *(const short8v*)ap;
        short8v a1 = *(const short8v*)(ap + 32);
        f32x4 e = {0.f, 0.f, 0.f, 0.f};
        e = __builtin_amdgcn_mfma_f32_16x16x32_bf16(a0, bq0, e, 0, 0, 0);
        e = __builtin_amdgcn_mfma_f32_16x16x32_bf16(a1, bq1, e, 0, 0, 0);
#pragma unroll
        for (int r = 0; r < 4; ++r) {
            float ee = e[r];
            float mn = fmaxf(m, ee);
            s = s * __expf(m - mn) + __expf(ee - mn);
            m = mn;
        }
    }
#pragma unroll
    for (int off = 16; off <= 32; off <<= 1) {
        float mo = __shfl_xor(m, off);
        float so = __shfl_xor(s, off);
        float mn = fmaxf(m, mo);
        s = s * __expf(m - mn) + so * __expf(mo - mn);
        m = mn;
    }
    if (lane < 16) {
        size_t o = ((size_t)js * B_ + b) * N_ + i0 + q;
        pmax[o] = m;
        psum[o] = s;
    }
}

__global__ __launch_bounds__(256) void rowmerge_kernel(const float* __restrict__ pmax,
                                                       const float* __restrict__ psum,
                                                       float* __restrict__ rm,
                                                       float* __restrict__ rsinv) {
    size_t i = (size_t)blockIdx.x * 256 + threadIdx.x;
    float m = -1e30f;
#pragma unroll
    for (int js = 0; js < JS_; ++js) m = fmaxf(m, pmax[(size_t)js * B_ * N_ + i]);
    float s = 0.f;
#pragma unroll
    for (int js = 0; js < JS_; ++js)
        s += psum[(size_t)js * B_ * N_ + i] * __expf(pmax[(size_t)js * B_ * N_ + i] - m);
    rm[i] = m;
    rsinv[i] = 1.f / s;
}

// --------- pass B (MFMA), n-split: energy -> attn (dbuf LDS) -> PV; partial XR + colsum out
__global__ __launch_bounds__(512, 4) void pv_mfma(const unsigned short* __restrict__ Qt,
                                                  const unsigned short* __restrict__ Vh,
                                                  const float* __restrict__ rm,
                                                  const float* __restrict__ rsinv,
                                                  unsigned short* __restrict__ pxr,
                                                  float* __restrict__ pcs) {
    __shared__ unsigned short saT[2][4096];   // [buf][m][n] bf16, 128B pitch, XOR-swizzled
    __shared__ float srm[NRANGE], srs[NRANGE];   // rm/rs for this block's n-range
    __shared__ float scs[8][2][16];
    const int tid = threadIdx.x;
    const int wave = tid >> 6, lane = tid & 63, q = lane & 15, g = lane >> 4;
    const int bid = blockIdx.x;
    const int b  = bid & 7;                // XCD-pinned: one batch per XCD
    const int rest = bid >> 3;
    const int m0 = (rest & 63) << 6;
    const int ns = rest >> 6;              // n-split index
    const int nbeg = ns * NRANGE;
    const int nb = wave & 3, mp = wave >> 2;
    const unsigned short* Qb = Qt + (size_t)b * N_ * CQK_;
    const unsigned short* Vb = Vh + (size_t)b * C_ * N_;

    // stage rm/rs for the n-range into LDS (one f32x4 per thread per array)
    *(f32x4*)&srm[4 * tid] = *(const f32x4*)(rm + (size_t)b * N_ + nbeg + 4 * tid);
    *(f32x4*)&srs[4 * tid] = *(const f32x4*)(rsinv + (size_t)b * N_ + nbeg + 4 * tid);

    short8v bqm[2][2];   // energy B-frags: Q columns m
#pragma unroll
    for (int mi = 0; mi < 2; ++mi) {
        const unsigned short* p = Qb + (size_t)(m0 + (mp * 2 + mi) * 16 + q) * CQK_ + 8 * g;
        bqm[mi][0] = *(const short8v*)p;
        bqm[mi][1] = *(const short8v*)(p + 32);
    }

    // preload tile-0 A-frags
    const unsigned short* ap0 = Qb + (size_t)(nbeg + nb * 16 + q) * CQK_ + 8 * g;
    short8v an0 = *(const short8v*)ap0;
    short8v an1 = *(const short8v*)(ap0 + 32);

    f32x4 acc[2][4];
#pragma unroll
    for (int ci = 0; ci < 2; ++ci)
#pragma unroll
        for (int mb = 0; mb < 4; ++mb) acc[ci][mb] = (f32x4){0.f, 0.f, 0.f, 0.f};
    float csum0 = 0.f, csum1 = 0.f;

    __syncthreads();   // srm/srs visible

    for (int n0 = nbeg; n0 < nbeg + NRANGE; n0 += 64) {
        const int cur = (n0 >> 6) & 1;
        // V-frags for current tile
        short8v vf[2][2];
#pragma unroll
        for (int ch = 0; ch < 2; ++ch)
#pragma unroll
            for (int ci = 0; ci < 2; ++ci)
                vf[ch][ci] = *(const short8v*)(Vb + (size_t)(wave * 32 + ci * 16 + q) * N_
                                               + n0 + ch * 32 + 8 * g);
        const int nrel = n0 - nbeg + nb * 16 + 4 * g;
        f32x4 rm4 = *(const f32x4*)&srm[nrel];
        f32x4 rs4 = *(const f32x4*)&srs[nrel];
        // ---- energy + attn tile
#pragma unroll
        for (int mi = 0; mi < 2; ++mi) {
            f32x4 e = {0.f, 0.f, 0.f, 0.f};
            e = __builtin_amdgcn_mfma_f32_16x16x32_bf16(an0, bqm[mi][0], e, 0, 0, 0);
            e = __builtin_amdgcn_mfma_f32_16x16x32_bf16(an1, bqm[mi][1], e, 0, 0, 0);
            const int mcol = (mp * 2 + mi) * 16 + q;
            float csl = 0.f;
            short4v pk;
#pragma unroll
            for (int r = 0; r < 4; ++r) {
                float a = __expf(e[r] - rm4[r]) * rs4[r];
                csl += a;
                pk[r] = (short)f2bf(a);
            }
            if (mi == 0) csum0 += csl; else csum1 += csl;
            const int byte = mcol * 128 + ((2 * (nb * 16 + 4 * g)) ^ ((mcol & 7) << 4));
            *(short4v*)((char*)saT + cur * 8192 + byte) = pk;
        }
        // ---- prefetch next tile A-frags
        const int n1 = (n0 + 64 < nbeg + NRANGE) ? n0 + 64 : nbeg;
        const unsigned short* apn = Qb + (size_t)(n1 + nb * 16 + q) * CQK_ + 8 * g;
        short8v an0n = *(const short8v*)apn;
        short8v an1n = *(const short8v*)(apn + 32);
        __syncthreads();   // attn tile visible (dbuf: single barrier per tile)
        // ---- PV
        __builtin_amdgcn_s_setprio(1);
#pragma unroll
        for (int ch = 0; ch < 2; ++ch) {
            short8v bfrag[4];
#pragma unroll
            for (int mb = 0; mb < 4; ++mb) {
                int row = mb * 16 + q;
                int byte = row * 128 + ((16 * (g + 4 * ch)) ^ ((row & 7) << 4));
                bfrag[mb] = *(const short8v*)((char*)saT + cur * 8192 + byte);
            }
#pragma unroll
            for (int ci = 0; ci < 2; ++ci)
#pragma unroll
                for (int mb = 0; mb < 4; ++mb)
                    acc[ci][mb] = __builtin_amdgcn_mfma_f32_16x16x32_bf16(vf[ch][ci], bfrag[mb],
                                                                          acc[ci][mb], 0, 0, 0);
        }
        __builtin_amdgcn_s_setprio(0);
        an0 = an0n; an1 = an1n;
    }

    // ---- partial column sums
    csum0 += __shfl_xor(csum0, 16); csum0 += __shfl_xor(csum0, 32);
    csum1 += __shfl_xor(csum1, 16); csum1 += __shfl_xor(csum1, 32);
    if (lane < 16) { scs[wave][0][q] = csum0; scs[wave][1][q] = csum1; }
    __syncthreads();
    if (tid < 64) {
        int mb = tid >> 4, qq = tid & 15;
        int base = (mb >> 1) * 4;
        float cs = 0.f;
#pragma unroll
        for (int w = 0; w < 4; ++w) cs += scs[base + w][mb & 1][qq];
        pcs[((size_t)ns * B_ + b) * N_ + m0 + tid] = cs;
    }
    // ---- partial XR out: bf16 [ns][b][m][c] (lane holds 4 consecutive c per (ci,mb))
    unsigned short* pb = pxr + ((size_t)ns * B_ + b) * N_ * 256;
#pragma unroll
    for (int ci = 0; ci < 2; ++ci) {
        int cb = wave * 32 + ci * 16 + 4 * g;
#pragma unroll
        for (int mb = 0; mb < 4; ++mb) {
            int m = m0 + mb * 16 + q;
            short4v pk;
#pragma unroll
            for (int r = 0; r < 4; ++r) pk[r] = (short)f2bf(acc[ci][mb][r]);
            *(short4v*)(pb + (size_t)m * 256 + cb) = pk;
        }
    }
}

// ------- reduce partials + diff, in place: dh[b][m][c] = bf16( xst - (p0+p1)/(1e-9+cs) )
__global__ __launch_bounds__(256) void reduce_diff(const unsigned short* __restrict__ pxr,
                                                   const float* __restrict__ pcs,
                                                   unsigned short* __restrict__ dh) {
    size_t i = (size_t)blockIdx.x * 256 + threadIdx.x;   // over B*N*C/8
    size_t e0 = i * 8;
    int m = (int)((e0 >> 8) & (N_ - 1));
    int b = (int)(e0 >> 20);
    float cs = pcs[(size_t)b * N_ + m] + pcs[((size_t)B_ + b) * N_ + m];
    float inv = 1.f / (1e-9f + cs);
    short8v p0 = *(const short8v*)(pxr + e0);
    short8v p1 = *(const short8v*)(pxr + (size_t)B_ * N_ * 256 + e0);
    short8v xv = *(const short8v*)(dh + e0);
    short8v o;
#pragma unroll
    for (int j = 0; j < 8; ++j) {
        float xr = (bf2f((unsigned short)p0[j]) + bf2f((unsigned short)p1[j])) * inv;
        o[j] = (short)f2bf(bf2f((unsigned short)xv[j]) - xr);
    }
    *(short8v*)(dh + e0) = o;
}

// ------- t-conv + finalize (MFMA): out = xs + leaky(bn(t))
__global__ __launch_bounds__(256, 4) void convt_kernel(const unsigned short* __restrict__ dh,
                                                       const unsigned short* __restrict__ wh,
                                                       const float* __restrict__ bt,
                                                       const float* __restrict__ xs,
                                                       float* __restrict__ out,
                                                       const float* __restrict__ gam,
                                                       const float* __restrict__ bet,
                                                       const float* __restrict__ mu,
                                                       const float* __restrict__ var) {
    const int tid = threadIdx.x, wave = tid >> 6, lane = tid & 63, q = lane & 15, g = lane >> 4;
    const int m0 = blockIdx.x * 64, c0 = blockIdx.y * 64, b = blockIdx.z;
    const unsigned short* db = dh + (size_t)b * N_ * 256;
    f32x4 acc[4];
#pragma unroll
    for (int j = 0; j < 4; ++j) acc[j] = (f32x4){0.f, 0.f, 0.f, 0.f};
    for (int ks = 0; ks < 8; ++ks) {
        short8v bw = *(const short8v*)(wh + (size_t)(c0 + wave * 16 + q) * 256 + ks * 32 + 8 * g);
#pragma unroll
        for (int j = 0; j < 4; ++j) {
            short8v ad = *(const short8v*)(db + (size_t)(m0 + j * 16 + q) * 256 + ks * 32 + 8 * g);
            acc[j] = __builtin_amdgcn_mfma_f32_16x16x32_bf16(ad, bw, acc[j], 0, 0, 0);
        }
    }
    const int c = c0 + wave * 16 + q;
    const float sc = rsqrtf(var[c] + 1e-5f) * gam[c];
    const float sh = bet[c] - mu[c] * sc;
    const float bb = bt[c];
#pragma unroll
    for (int j = 0; j < 4; ++j) {
        size_t off = ((size_t)b * C_ + c) * N_ + m0 + j * 16 + 4 * g;
        float4 xv = *(const float4*)(xs + off);
        float4 o;
        float tn;
        tn = (acc[j][0] + bb) * sc + sh; o.x = xv.x + (tn >= 0.f ? tn : 0.2f * tn);
        tn = (acc[j][1] + bb) * sc + sh; o.y = xv.y + (tn >= 0.f ? tn : 0.2f * tn);
        tn = (acc[j][2] + bb) * sc + sh; o.z = xv.z + (tn >= 0.f ? tn : 0.2f * tn);
        tn = (acc[j][3] + bb) * sc + sh; o.w = xv.w + (tn >= 0.f ? tn : 0.2f * tn);
        *(float4*)(out + off) = o;
    }
}

// ----------------------------------------------------------------------------------------
extern "C" void kernel_launch(void* const* d_in, const int* in_sizes, int n_in,
                              void* d_out, int out_size, void* d_ws, size_t ws_size,
                              hipStream_t stream) {
    (void)in_sizes; (void)n_in; (void)out_size; (void)ws_size;
    const float* x   = (const float*)d_in[0];
    const float* xyz = (const float*)d_in[1];
    const float* wqk = (const float*)d_in[2];
    const float* bqk = (const float*)d_in[3];
    const float* wv  = (const float*)d_in[4];
    const float* bv  = (const float*)d_in[5];
    const float* wt  = (const float*)d_in[6];
    const float* bt  = (const float*)d_in[7];
    const float* gam = (const float*)d_in[8];
    const float* bet = (const float*)d_in[9];
    const float* mu  = (const float*)d_in[10];
    const float* var = (const float*)d_in[11];
    float* out = (float*)d_out;

    const size_t M8 = (size_t)B_ * C_ * N_;   // 8M elements
    float* ws = (float*)d_ws;
    size_t off = 0;
    float* xs = ws + off;                              off += M8;       // fp32 [b][c][n] 32MB
    unsigned short* xst = (unsigned short*)(ws + off); off += M8 / 2;   // bf16 [b][n][c] 16MB
    unsigned short* Qt  = (unsigned short*)(ws + off); off += M8 / 8;   // bf16 [b][n][64] 4MB
    unsigned short* Vh  = (unsigned short*)(ws + off); off += M8 / 2;   // bf16 [b][c][n] 16MB
    unsigned short* wh  = (unsigned short*)(ws + off); off += 81920;    // bf16 weights
    float* pmax = ws + off; off += (size_t)JS_ * B_ * N_;
    float* psum = ws + off; off += (size_t)JS_ * B_ * N_;
    float* rmb  = ws + off; off += (size_t)B_ * N_;
    float* rsb  = ws + off; off += (size_t)B_ * N_;
    float* pcs  = ws + off; off += (size_t)NSPLIT * B_ * N_;
    unsigned short* pxr = (unsigned short*)(ws + off); off += M8;       // bf16 [2][b][m][c] 32MB
    unsigned short* dhb = xst;   // reduce_diff updates xst in place -> dh

    wcvt_kernel<<<dim3(144), dim3(256), 0, stream>>>(wqk, wv, wt, wh);
    addt_kernel<<<dim3(N_ / 64, C_ / 64, B_), dim3(256), 0, stream>>>(x, xyz, xs, xst);
    convq_kernel<<<dim3(N_ / 64, B_), dim3(256), 0, stream>>>(xst, wh, bqk, Qt);
    convv_kernel<<<dim3(N_ / 64, C_ / 64, B_), dim3(256), 0, stream>>>(xst, wh + 16384, bv, Vh);
    rowstats_mfma<<<dim3(B_ * (N_ / 64) * JS_), dim3(256), 0, stream>>>(Qt, pmax, psum);
    rowmerge_kernel<<<dim3(B_ * N_ / 256), dim3(256), 0, stream>>>(pmax, psum, rmb, rsb);
    pv_mfma<<<dim3(B_ * (N_ / 64) * NSPLIT), dim3(512), 0, stream>>>(Qt, Vh, rmb, rsb, pxr, pcs);
    reduce_diff<<<dim3(B_ * N_ * C_ / 8 / 256), dim3(256), 0, stream>>>(pxr, pcs, dhb);
    convt_kernel<<<dim3(N_ / 64, C_ / 64, B_), dim3(256), 0, stream>>>(
        dhb, wh + 81920, bt, xs, out, gam, bet, mu, var);
}